// Round 2
// baseline (344.945 us; speedup 1.0000x reference)
//
#include <hip/hip_runtime.h>

// Correlation1D on MI355X (gfx950), round 2.
// out[b,d,h,w] = (1/256) * sum_c in1[b,c,h,w] * in2[b,c,h,w+d-40]
// B=8 C=256 H=96 W=192 D=81 PAD=40.
//
// R2 design: 3072 single-wave blocks (one per (b,h,q), q = 48-wide w-chunk).
// Single wave => no __syncthreads at all (same-wave LDS ops are in-order):
// each wave is an independent load->cvt->MFMA pipeline; 12 blocks/CU.
// Only B (j-window, 128 cols) staged in LDS (10.2 KB); A fragments loaded
// directly from global (16-lane x 64B segments, L1-coalesced, read once).

typedef __attribute__((ext_vector_type(8))) short short8;     // 8 bf16
typedef __attribute__((ext_vector_type(4))) float float4v;
typedef __attribute__((ext_vector_type(4))) int int4v;

__device__ __forceinline__ unsigned short f2bf(float f) {
  // round-to-nearest-even fp32 -> bf16
  unsigned int u = __float_as_uint(f);
  return (unsigned short)((u + 0x7FFFu + ((u >> 16) & 1u)) >> 16);
}

__global__ __launch_bounds__(64, 3) void corr1d_kernel(
    const float* __restrict__ in1, const float* __restrict__ in2,
    float* __restrict__ out) {
  constexpr int W = 192, H = 96, C = 256, D = 81;
  constexpr int HW = H * W;          // c-stride in elements
  constexpr int KC = 32;             // k-chunk (one MFMA K per stage)
  constexpr int SB = 40;             // B LDS k-stride (32+8 pad, b128-aligned, conflict-free)
  constexpr int WCH = 48;            // w-chunk per block

  // LDS: B stage [j_rel 0..127][k 0..31 (+pad)] = 128*40 ushorts = 10240 B.
  // Epilogue overlays it as float E[41][48] = 7872 B.
  __shared__ __align__(16) unsigned short smem[128 * SB];
  unsigned short* B_l = smem;
  float* E = (float*)smem;

  const int bx = blockIdx.x;
  const int q  = bx & 3;             // w-chunk, fastest -> adjacent blocks share in2 halo
  const int bh = bx >> 2;
  const int b = bh / H;
  const int h = bh % H;
  const int lane = threadIdx.x;      // 0..63 (single wave)
  const int l15 = lane & 15;
  const int lq  = lane >> 4;

  const int w0abs = WCH * q;                          // block w start; j = w0abs + j_rel
  const int lo = (w0abs - 40 > 0) ? (w0abs - 40) : 0; // valid in2 w' range
  const int hi = (w0abs + 88 < W) ? (w0abs + 88) : W;
  const int nbg = (hi - lo) >> 2;                     // B col groups (22 edge, 32 interior)
  const int jr0 = lo + 40 - w0abs;                    // j_rel of first staged col

  // zero invalid B halo cols once (edge blocks only; never re-staged)
  if (q == 0) {
    for (int t = lane; t < 160; t += 64) {            // j_rel [0,40) x 4 granules
      int j = t >> 2, kg = t & 3;
      *(int4v*)(B_l + j * SB + kg * 8) = (int4v){0, 0, 0, 0};
    }
  } else if (q == 3) {
    for (int t = lane; t < 160; t += 64) {            // j_rel [88,128)
      int j = 88 + (t >> 2), kg = t & 3;
      *(int4v*)(B_l + j * SB + kg * 8) = (int4v){0, 0, 0, 0};
    }
  }

  float4v acc[3][6];
#pragma unroll
  for (int i = 0; i < 3; ++i)
#pragma unroll
    for (int jj = 0; jj < 6; ++jj) acc[i][jj] = (float4v){0.f, 0.f, 0.f, 0.f};

  const int base = (b * C * H + h) * W;
  const float* a_col = in1 + base + w0abs + l15;      // + 16*i + c*HW
  const int ntasks = nbg * 4;                         // 88 or 128

  for (int c0 = 0; c0 < C; c0 += KC) {
    // ---- A fragments direct from global: A[m=l15][k=8*lq+t], w = w0abs+16i+l15
    // issued first so their latency overlaps the B staging below
    float a_raw[3][8];
#pragma unroll
    for (int i = 0; i < 3; ++i)
#pragma unroll
      for (int t = 0; t < 8; ++t)
        a_raw[i][t] = a_col[(c0 + 8 * lq + t) * HW + 16 * i];

    // ---- stage B chunk into LDS (cg fastest -> coalesced loads, conflict-free writes)
    for (int t = lane; t < ntasks; t += 64) {
      const int cg = t & 3;                           // 8-channel subgroup
      const int wg = t >> 2;                          // 4-col group
      const int gaddr = base + (c0 + cg * 8) * HW + lo + 4 * wg;
      float4v v[8];
#pragma unroll
      for (int i = 0; i < 8; ++i) v[i] = *(const float4v*)(in2 + gaddr + i * HW);
      const int jr = jr0 + 4 * wg;
#pragma unroll
      for (int x = 0; x < 4; ++x) {
        unsigned short o[8];
#pragma unroll
        for (int i = 0; i < 8; ++i) o[i] = f2bf(v[i][x]);
        *(int4v*)(B_l + (jr + x) * SB + cg * 8) = *(const int4v*)o;
      }
    }

    // ---- build A frags (A data arrived while B was loading)
    short8 af[3];
#pragma unroll
    for (int i = 0; i < 3; ++i) {
      unsigned short o[8];
#pragma unroll
      for (int t = 0; t < 8; ++t) o[t] = f2bf(a_raw[i][t]);
      af[i] = *(const short8*)o;
    }

    // ---- compute: 8 j-tiles, band of 6 per w-tile (single wave, no barrier)
#pragma unroll
    for (int jt = 0; jt < 8; ++jt) {
      short8 bfr = *(const short8*)(B_l + (16 * jt + l15) * SB + 8 * lq);
#pragma unroll
      for (int i = 0; i < 3; ++i) {
        const int jj = jt - i;                        // compile-time after unroll
        if (jj >= 0 && jj < 6)
          acc[i][jj] = __builtin_amdgcn_mfma_f32_16x16x32_bf16(
              af[i], bfr, acc[i][jj], 0, 0, 0);
      }
    }
  }

  // ---- epilogue: C/D layout row(w)=4*lq+r, col(j)=l15 -> d = 16jj+l15-4lq-r.
  // Two d-phases through LDS overlay; float4 coalesced stores.
  const float scale = 1.0f / 256.0f;
#pragma unroll
  for (int p = 0; p < 2; ++p) {
    const int dlo = p ? 41 : 0;
    const int nd  = p ? 40 : 41;
#pragma unroll
    for (int i = 0; i < 3; ++i)
#pragma unroll
      for (int jj = 0; jj < 6; ++jj)
#pragma unroll
        for (int r = 0; r < 4; ++r) {
          const int d  = 16 * jj + l15 - 4 * lq - r;
          const int wr = 16 * i + 4 * lq + r;
          if (d >= dlo && d < dlo + nd)
            E[(d - dlo) * 48 + wr] = acc[i][jj][r] * scale;
        }
    for (int t = lane; t < nd * 12; t += 64) {
      const int dr = t / 12, g = t % 12;
      float4v val = *(const float4v*)(E + dr * 48 + 4 * g);
      *(float4v*)(out + ((b * D + dlo + dr) * H + h) * W + w0abs + 4 * g) = val;
    }
  }
}

extern "C" void kernel_launch(void* const* d_in, const int* in_sizes, int n_in,
                              void* d_out, int out_size, void* d_ws, size_t ws_size,
                              hipStream_t stream) {
  const float* in1 = (const float*)d_in[0];
  const float* in2 = (const float*)d_in[1];
  float* out = (float*)d_out;
  (void)in_sizes; (void)n_in; (void)out_size; (void)d_ws; (void)ws_size;
  corr1d_kernel<<<dim3(3072), dim3(64), 0, stream>>>(in1, in2, out);
}

// Round 3
// 342.768 us; speedup vs baseline: 1.0064x; 1.0064x over previous
//
#include <hip/hip_runtime.h>

// Correlation1D on MI355X (gfx950), round 3.
// out[b,d,h,w] = (1/256) * sum_c in1[b,c,h,w] * in2[b,c,h,w+d-40]
// B=8 C=256 H=96 W=192 D=81 PAD=40.
//
// R3 = R2 structure (single-wave blocks, WCH=48, SB=40, 16x16x32 bf16 MFMA)
// with m97-style load discipline: burst-issue all global loads for a half-K
// chunk before a single wait, and prefetch the next chunk's loads before the
// current chunk's MFMAs so every wave keeps ~12 KB in flight continuously.

typedef __attribute__((ext_vector_type(8))) short short8;     // 8 bf16
typedef __attribute__((ext_vector_type(4))) float float4v;
typedef __attribute__((ext_vector_type(4))) int int4v;

__device__ __forceinline__ unsigned short f2bf(float f) {
  // round-to-nearest-even fp32 -> bf16
  unsigned int u = __float_as_uint(f);
  return (unsigned short)((u + 0x7FFFu + ((u >> 16) & 1u)) >> 16);
}

__global__ __launch_bounds__(64, 3) void corr1d_kernel(
    const float* __restrict__ in1, const float* __restrict__ in2,
    float* __restrict__ out) {
  constexpr int W = 192, H = 96, C = 256, D = 81;
  constexpr int HW = H * W;          // c-stride in elements
  constexpr int SB = 40;             // B LDS k-stride (32+8 pad, conflict-free)

  // LDS: B tile [j_rel 0..127][k 0..31 (+pad)] = 10240 B; epilogue overlays
  // float E[41][48] = 7872 B. 12 blocks/CU -> 123 KB.
  __shared__ __align__(16) unsigned short smem[128 * SB];
  unsigned short* B_l = smem;
  float* E = (float*)smem;

  const int bx = blockIdx.x;
  const int q  = bx & 3;             // w-chunk fastest: adjacent blocks share halo
  const int bh = bx >> 2;
  const int b = bh / H;
  const int h = bh % H;
  const int lane = threadIdx.x;      // single wave
  const int l15 = lane & 15;
  const int lq  = lane >> 4;

  const int w0abs = 48 * q;
  const int lo = (w0abs - 40 > 0) ? (w0abs - 40) : 0;
  const int hi = (w0abs + 88 < W) ? (w0abs + 88) : W;
  const int nbg = (hi - lo) >> 2;                     // 4-col groups (22 or 32)
  const int jr0 = lo + 40 - w0abs;

  // zero invalid halo rows once (edge blocks only; never re-staged)
  if (q == 0) {
    for (int t = lane; t < 160; t += 64) {
      int j = t >> 2, g = t & 3;
      *(int4v*)(B_l + j * SB + 8 * g) = (int4v){0, 0, 0, 0};
    }
  } else if (q == 3) {
    for (int t = lane; t < 160; t += 64) {
      int j = 88 + (t >> 2), g = t & 3;
      *(int4v*)(B_l + j * SB + 8 * g) = (int4v){0, 0, 0, 0};
    }
  }

  float4v acc[3][6];
#pragma unroll
  for (int i = 0; i < 3; ++i)
#pragma unroll
    for (int jj = 0; jj < 6; ++jj) acc[i][jj] = (float4v){0.f, 0.f, 0.f, 0.f};

  const int base = (b * C * H + h) * W;
  const float* a_col = in1 + base + w0abs + l15;

  // per-lane B task: one 4-col x 8-k granule per half-K burst
  const bool bact = lane < 2 * nbg;
  const int bcg = lane & 1;                           // 8-k subgroup in half
  const int bwg = lane >> 1;                          // 4-col group
  const float* bsrc = in2 + base + lo + 4 * bwg;
  const int brow0 = jr0 + 4 * bwg;

  float4v bv[8];                                      // 32 VGPRs prefetch buffer
  float a_raw[3][8];                                  // 24 VGPRs

  auto burstB = [&](int c0, int h2) {                 // issue 8 float4 loads
    if (bact) {
      const float* p = bsrc + (c0 + 16 * h2 + 8 * bcg) * HW;
#pragma unroll
      for (int i = 0; i < 8; ++i) bv[i] = *(const float4v*)(p + i * HW);
    }
  };
  auto stageB = [&](int h2) {                         // cvt + 4x ds_write_b128
    if (bact) {
      const int ko = 16 * h2 + 8 * bcg;
#pragma unroll
      for (int x = 0; x < 4; ++x) {
        unsigned short o[8];
#pragma unroll
        for (int i = 0; i < 8; ++i) o[i] = f2bf(bv[i][x]);
        *(int4v*)(B_l + (brow0 + x) * SB + ko) = *(const int4v*)o;
      }
    }
  };
  auto burstA = [&](int c0) {                         // issue 24 dword loads
#pragma unroll
    for (int i2 = 0; i2 < 3; ++i2)
#pragma unroll
      for (int t = 0; t < 8; ++t)
        a_raw[i2][t] = a_col[(c0 + 8 * lq + t) * HW + 16 * i2];
  };

  // prologue: prefetch chunk 0
  burstA(0);
  burstB(0, 0);

  for (int c0 = 0; c0 < C; c0 += 32) {
    stageB(0);                       // consume half0 (prefetched last iter)
    burstB(c0, 1);                   // issue half1 immediately
    short8 af[3];
#pragma unroll
    for (int i = 0; i < 3; ++i) {    // cvt A while half1 is in flight
      unsigned short o[8];
#pragma unroll
      for (int t = 0; t < 8; ++t) o[t] = f2bf(a_raw[i][t]);
      af[i] = *(const short8*)o;
    }
    stageB(1);                       // consume half1
    if (c0 + 32 < C) {               // prefetch next chunk before MFMAs
      burstA(c0 + 32);
      burstB(c0 + 32, 0);
    }
    // fragments + MFMA (next chunk's loads stay in flight through this)
#pragma unroll
    for (int jt = 0; jt < 8; ++jt) {
      short8 bfr = *(const short8*)(B_l + (16 * jt + l15) * SB + 8 * lq);
#pragma unroll
      for (int i = 0; i < 3; ++i) {
        const int jj = jt - i;
        if (jj >= 0 && jj < 6)
          acc[i][jj] = __builtin_amdgcn_mfma_f32_16x16x32_bf16(
              af[i], bfr, acc[i][jj], 0, 0, 0);
      }
    }
  }

  // epilogue: C/D layout row(w)=4*lq+r, col(j)=l15 -> d = 16jj+l15-4lq-r.
  // Two d-phases through LDS overlay; float4 coalesced stores. (Proven in R2.)
  const float scale = 1.0f / 256.0f;
#pragma unroll
  for (int p = 0; p < 2; ++p) {
    const int dlo = p ? 41 : 0;
    const int nd  = p ? 40 : 41;
#pragma unroll
    for (int i = 0; i < 3; ++i)
#pragma unroll
      for (int jj = 0; jj < 6; ++jj)
#pragma unroll
        for (int r = 0; r < 4; ++r) {
          const int d  = 16 * jj + l15 - 4 * lq - r;
          const int wr = 16 * i + 4 * lq + r;
          if (d >= dlo && d < dlo + nd)
            E[(d - dlo) * 48 + wr] = acc[i][jj][r] * scale;
        }
    for (int t = lane; t < nd * 12; t += 64) {
      const int dr = t / 12, g = t % 12;
      float4v val = *(const float4v*)(E + dr * 48 + 4 * g);
      *(float4v*)(out + ((b * D + dlo + dr) * H + h) * W + w0abs + 4 * g) = val;
    }
  }
}

extern "C" void kernel_launch(void* const* d_in, const int* in_sizes, int n_in,
                              void* d_out, int out_size, void* d_ws, size_t ws_size,
                              hipStream_t stream) {
  const float* in1 = (const float*)d_in[0];
  const float* in2 = (const float*)d_in[1];
  float* out = (float*)d_out;
  (void)in_sizes; (void)n_in; (void)out_size; (void)d_ws; (void)ws_size;
  corr1d_kernel<<<dim3(3072), dim3(64), 0, stream>>>(in1, in2, out);
}

// Round 4
// 325.522 us; speedup vs baseline: 1.0597x; 1.0530x over previous
//
#include <hip/hip_runtime.h>

// Correlation1D on MI355X (gfx950), round 4.
// out[b,d,h,w] = (1/256) * sum_c in1[b,c,h,w] * in2[b,c,h,w+d-40]
// B=8 C=256 H=96 W=192 D=81 PAD=40.
//
// R4: full-row 256-thread blocks (768 = 3/CU), staging via async
// __builtin_amdgcn_global_load_lds (fp32, zero VGPR cost -> compiler cannot
// serialize the burst; 48 loads in flight per wave). LDS [k][col] fp32,
// row stride 194 (2-way bank aliasing = free). fp32->bf16 at fragment read.
// Halo zeros are a lane predicate, not stored. Verified 16x16x32 MFMA band.

typedef __attribute__((ext_vector_type(8))) short short8;     // 8 bf16
typedef __attribute__((ext_vector_type(4))) float float4v;

__device__ __forceinline__ unsigned short f2bf(float f) {
  // round-to-nearest-even fp32 -> bf16
  unsigned int u = __float_as_uint(f);
  return (unsigned short)((u + 0x7FFFu + ((u >> 16) & 1u)) >> 16);
}

__device__ __forceinline__ void glds4(const float* g, float* l) {
  __builtin_amdgcn_global_load_lds(
      (const __attribute__((address_space(1))) void*)g,
      (__attribute__((address_space(3))) void*)l, 4, 0, 0);
}

__global__ __launch_bounds__(256, 3) void corr1d_kernel(
    const float* __restrict__ in1, const float* __restrict__ in2,
    float* __restrict__ out) {
  constexpr int W = 192, H = 96, C = 256, D = 81;
  constexpr int HW = H * W;          // c-stride in elements
  constexpr int KC = 32;             // channels per chunk
  constexpr int SR = 194;            // LDS row stride (floats): 4*SR%32==8 -> 2-way
  constexpr int ES = 196;            // epilogue row stride (16B-aligned rows)

  // LDS: A[32][194] fp32 + B[32][194] fp32 = 49664 B -> 3 blocks/CU (149 KB).
  // Epilogue overlays as float E[41][196] (32144 B).
  __shared__ __align__(16) float smem[2 * KC * SR];
  float* As = smem;
  float* Bs = smem + KC * SR;
  float* E  = smem;

  const int bh = blockIdx.x;
  const int b = bh / H, h = bh % H;
  const int tid = threadIdx.x;
  const int lane = tid & 63;
  const int wv = tid >> 6;           // wave 0..3, owns w-tiles 3wv..3wv+2
  const int l15 = lane & 15, lq = lane >> 4;
  const int base = (b * C * H + h) * W;

  float4v acc[3][6];
#pragma unroll
  for (int i = 0; i < 3; ++i)
#pragma unroll
    for (int jj = 0; jj < 6; ++jj) acc[i][jj] = (float4v){0.f, 0.f, 0.f, 0.f};

  for (int m = 0; m < C / KC; ++m) {
    const int c0 = KC * m;
    __syncthreads();                 // previous chunk's readers done

    // ---- stage: wave wv handles k rows 8wv..8wv+7, 3 x 256B per input-row.
    // 48 async direct-to-LDS loads per wave, no result registers, one wait
    // (vmcnt(0)) folded into the next barrier.
#pragma unroll
    for (int r = 0; r < 8; ++r) {
      const int k = 8 * wv + r;
      const float* g1 = in1 + base + (c0 + k) * HW + lane;
      const float* g2 = in2 + base + (c0 + k) * HW + lane;
      float* lA = As + k * SR;
      float* lB = Bs + k * SR;
#pragma unroll
      for (int g = 0; g < 3; ++g) {
        glds4(g1 + 64 * g, lA + 64 * g);
        glds4(g2 + 64 * g, lB + 64 * g);
      }
    }
    __syncthreads();                 // compiler emits s_waitcnt vmcnt(0) first

    // ---- fragments (fp32 LDS -> bf16 regs) + banded MFMA
    short8 af[3];
#pragma unroll
    for (int i = 0; i < 3; ++i) {
      const float* ap = As + 48 * wv + 16 * i + l15;
      unsigned short o[8];
#pragma unroll
      for (int t = 0; t < 8; ++t) o[t] = f2bf(ap[(8 * lq + t) * SR]);
      af[i] = *(const short8*)o;
    }
#pragma unroll
    for (int jt = 0; jt < 8; ++jt) {
      const int j = 16 * (3 * wv + jt) + l15;     // padded j coord
      const bool ok = (j >= 40) && (j < 232);     // in2 col = j-40
      const float* bp = Bs + (ok ? (j - 40) : 0);
      unsigned short o[8];
#pragma unroll
      for (int t = 0; t < 8; ++t) {
        float v = ok ? bp[(8 * lq + t) * SR] : 0.0f;
        o[t] = f2bf(v);
      }
      short8 bfr = *(const short8*)o;
#pragma unroll
      for (int i = 0; i < 3; ++i) {
        const int jj = jt - i;                    // compile-time after unroll
        if (jj >= 0 && jj < 6)
          acc[i][jj] = __builtin_amdgcn_mfma_f32_16x16x32_bf16(
              af[i], bfr, acc[i][jj], 0, 0, 0);
      }
    }
  }

  // ---- epilogue: D layout col(j)=l15, row(w)=4lq+r -> d = 16jj+l15-4lq-r.
  // Two d-phases through LDS overlay; full-row float4 coalesced stores.
  const float scale = 1.0f / 256.0f;
#pragma unroll
  for (int p = 0; p < 2; ++p) {
    const int dlo = p ? 41 : 0;
    const int nd  = p ? 40 : 41;
    __syncthreads();                 // stage buffer / previous E free
#pragma unroll
    for (int i = 0; i < 3; ++i)
#pragma unroll
      for (int jj = 0; jj < 6; ++jj)
#pragma unroll
        for (int r = 0; r < 4; ++r) {
          const int d = 16 * jj + l15 - 4 * lq - r;
          const int w = 48 * wv + 16 * i + 4 * lq + r;
          if (d >= dlo && d < dlo + nd)
            E[(d - dlo) * ES + w] = acc[i][jj][r] * scale;
        }
    __syncthreads();
    for (int t = tid; t < nd * 48; t += 256) {
      const int dr = t / 48, g = t % 48;
      float4v val = *(const float4v*)(E + dr * ES + 4 * g);
      *(float4v*)(out + ((b * D + dlo + dr) * H + h) * W + 4 * g) = val;
    }
  }
}

extern "C" void kernel_launch(void* const* d_in, const int* in_sizes, int n_in,
                              void* d_out, int out_size, void* d_ws, size_t ws_size,
                              hipStream_t stream) {
  const float* in1 = (const float*)d_in[0];
  const float* in2 = (const float*)d_in[1];
  float* out = (float*)d_out;
  (void)in_sizes; (void)n_in; (void)out_size; (void)d_ws; (void)ws_size;
  corr1d_kernel<<<dim3(768), dim3(256), 0, stream>>>(in1, in2, out);
}